// Round 2
// baseline (17161.559 us; speedup 1.0000x reference)
//
#include <hip/hip_runtime.h>
#include <hip/hip_bf16.h>
#include <hip/hip_cooperative_groups.h>

namespace cg = cooperative_groups;

#define B_   256
#define T_   64
#define OBS_ 1024
#define ACT_ 6
#define STO_ 32
#define HID_ 1024
#define DET_ 1024
#define NTHREADS 131072   // 256 blocks * 512 threads

using bf16 = __bf16;
typedef __attribute__((ext_vector_type(8))) __bf16 bf16x8;
typedef __attribute__((ext_vector_type(4))) float f32x4;

struct Params {
  const float *obs, *actions, *eps_post;
  const float *in_w1, *in_b1, *in_w2, *in_b2;
  const float *gru_wih, *gru_whh, *gru_bih, *gru_bhh;
  const float *pr_w1, *pr_b1, *pr_w2, *pr_b2, *pr_mw, *pr_mb, *pr_sw, *pr_sb;
  const float *po_w1, *po_b1, *po_w2, *po_b2, *po_mw, *po_mb, *po_sw, *po_sb;
  float *feat, *pm, *ps, *qm, *qs;
  bf16 *w_in2b, *w_wihb, *w_whhb, *w_pr1b, *w_pr2b, *w_po1b, *w_po2b, *w_phb, *w_qhb;
  bf16 *x1b, *x2b, *hb, *p1b, *q1b, *p2b, *q2b, *obsb;
  float *hf, *gi, *gh;
};

// wave-tile job: 16 rows x 64 cols of out = A[256,K]@W[N,K]^T over K-range [kbeg,kend)
struct TileJob {
  const bf16* A; const bf16* W; const float* bias;
  bf16* outB; float* outF;
  int lda, ldw, ldo, akoff;
  int m0, n0, kbeg, kend;
  int ksub, lgS, S, relu, valid;
};

__device__ __forceinline__ f32x4 MF(bf16x8 a, bf16x8 b, f32x4 c) {
  return __builtin_amdgcn_mfma_f32_16x16x32_bf16(a, b, c, 0, 0, 0);
}

// Executes one wave-tile (or idles) with K-split LDS reduction.
// EVERY thread must call this exactly once per stage (single __syncthreads inside).
__device__ __forceinline__ void run_job(const TileJob& j, float* sh) {
  const int tid = threadIdx.x, lane = tid & 63, wv = tid >> 6;
  const int l15 = lane & 15, kq = (lane >> 4) << 3, rq = (lane >> 4) << 2;
  f32x4 a0{0.f,0.f,0.f,0.f}, a1 = a0, a2 = a0, a3 = a0;
  if (j.valid) {
    const bf16* ap  = j.A + (size_t)(j.m0 + l15) * j.lda + (kq - j.akoff);
    const bf16* wp0 = j.W + (size_t)(j.n0 + l15) * j.ldw + kq;
    const size_t ws16 = (size_t)16 * j.ldw;
    #pragma unroll 4
    for (int k = j.kbeg; k < j.kend; k += 32) {
      bf16x8 af = *(const bf16x8*)(ap + k);
      const bf16* wp = wp0 + k;
      a0 = MF(af, *(const bf16x8*)(wp            ), a0);
      a1 = MF(af, *(const bf16x8*)(wp +     ws16 ), a1);
      a2 = MF(af, *(const bf16x8*)(wp + 2 * ws16 ), a2);
      a3 = MF(af, *(const bf16x8*)(wp + 3 * ws16 ), a3);
    }
  }
  if (j.valid && j.ksub) {          // non-leader: park partial in LDS
    const int sb = ((wv >> j.lgS) * (j.S - 1) + j.ksub - 1) * 1088;
    f32x4 aa[4] = {a0, a1, a2, a3};
    #pragma unroll
    for (int t2 = 0; t2 < 4; ++t2)
      #pragma unroll
      for (int r = 0; r < 4; ++r)
        sh[sb + (rq + r) * 68 + t2 * 16 + l15] = aa[t2][r];
  }
  __syncthreads();
  if (j.valid && j.ksub == 0) {     // leader: reduce + epilogue
    f32x4 aa[4] = {a0, a1, a2, a3};
    for (int s = 1; s < j.S; ++s) {
      const int sb = ((wv >> j.lgS) * (j.S - 1) + s - 1) * 1088;
      #pragma unroll
      for (int t2 = 0; t2 < 4; ++t2)
        #pragma unroll
        for (int r = 0; r < 4; ++r)
          aa[t2][r] += sh[sb + (rq + r) * 68 + t2 * 16 + l15];
    }
    #pragma unroll
    for (int t2 = 0; t2 < 4; ++t2) {
      const int n = j.n0 + t2 * 16 + l15;
      const float bv = j.bias ? j.bias[n] : 0.f;
      #pragma unroll
      for (int r = 0; r < 4; ++r) {
        float v = aa[t2][r] + bv;
        if (j.relu) v = fmaxf(v, 0.f);
        const size_t off = (size_t)(j.m0 + rq + r) * j.ldo + n;
        if (j.outB) j.outB[off] = (bf16)v;
        if (j.outF) j.outF[off] = v;
      }
    }
  }
}

__global__ __launch_bounds__(512, 2) void rssm_kern(Params P) {
  cg::grid_group grid = cg::this_grid();
  __shared__ float sh[6 * 1088];   // 6 reduce slots of 16x68 f32 (25.5 KB)
  const int tid  = threadIdx.x;
  const int wv   = tid >> 6;
  const int wgid = blockIdx.x * 8 + wv;   // 0..2047
  const int gt   = blockIdx.x * 512 + tid; // 0..131071

  // ---- stage 0 (once): weights fp32->bf16, state init ----
  {
    auto cv = [&](const float* s, bf16* d, int n) {
      for (int i = gt; i < n; i += NTHREADS) d[i] = (bf16)s[i];
    };
    cv(P.in_w2,   P.w_in2b, HID_ * HID_);
    cv(P.gru_wih, P.w_wihb, 3 * DET_ * HID_);
    cv(P.gru_whh, P.w_whhb, 3 * DET_ * DET_);
    cv(P.pr_w1,   P.w_pr1b, HID_ * DET_);
    cv(P.pr_w2,   P.w_pr2b, HID_ * HID_);
    cv(P.po_w1,   P.w_po1b, HID_ * (DET_ + OBS_));
    cv(P.po_w2,   P.w_po2b, HID_ * HID_);
    cv(P.pr_mw,   P.w_phb,               STO_ * HID_);
    cv(P.pr_sw,   P.w_phb + STO_ * HID_, STO_ * HID_);
    cv(P.po_mw,   P.w_qhb,               STO_ * HID_);
    cv(P.po_sw,   P.w_qhb + STO_ * HID_, STO_ * HID_);
    for (int i = gt; i < B_ * HID_; i += NTHREADS) {
      P.x1b[i] = (bf16)fmaxf(P.in_b1[i & (HID_ - 1)], 0.f);  // z0=0,a0=0
      P.hb[i] = (bf16)0.f;
      P.hf[i] = 0.f;
    }
  }
  grid.sync();

  for (int t = 0; t < T_; ++t) {
    // ---- S1: x2 = relu(x1@in_w2^T+b2)  [512 items] ; gh = h@whh^T+bhh [1536 items] ----
    {
      TileJob j; j.valid = 0; j.ksub = 0; j.S = 1; j.lgS = 0;
      if (wgid < 512) {
        const int tile = wgid >> 1, ks = wgid & 1;
        j = { P.x1b, P.w_in2b, P.in_b2, P.x2b, nullptr,
              HID_, HID_, HID_, 0,
              (tile & 15) * 16, (tile >> 4) * 64, ks * 512, ks * 512 + 512,
              ks, 1, 2, 1, 1 };
      } else {
        const int it = wgid - 512, tile = it >> 1, ks = it & 1;
        j = { P.hb, P.w_whhb, P.gru_bhh, nullptr, P.gh,
              DET_, DET_, 3 * DET_, 0,
              (tile & 15) * 16, (tile >> 4) * 64, ks * 512, ks * 512 + 512,
              ks, 1, 2, 0, 1 };
      }
      run_job(j, sh);
    }
    grid.sync();

    // ---- S2: gi = x2@wih^T+bih  [1536 items] ----
    {
      TileJob j; j.valid = 0; j.ksub = 0; j.S = 1; j.lgS = 0;
      if (wgid < 1536) {
        const int tile = wgid >> 1, ks = wgid & 1;
        j = { P.x2b, P.w_wihb, P.gru_bih, nullptr, P.gi,
              HID_, HID_, 3 * DET_, 0,
              (tile & 15) * 16, (tile >> 4) * 64, ks * 512, ks * 512 + 512,
              ks, 1, 2, 0, 1 };
      }
      run_job(j, sh);
    }
    grid.sync();

    // ---- S3: GRU elementwise + feat h-part + obs->bf16 ----
    #pragma unroll
    for (int rep = 0; rep < 2; ++rep) {
      const int idx = gt + rep * NTHREADS;        // < 262144
      const int m = idx >> 10, i = idx & 1023;
      const size_t base = (size_t)m * 3072;
      float r  = P.gi[base + i]        + P.gh[base + i];
      float u  = P.gi[base + 1024 + i] + P.gh[base + 1024 + i];
      float nn = P.gi[base + 2048 + i];
      float hn = P.gh[base + 2048 + i];
      r = 1.f / (1.f + __expf(-r));
      u = 1.f / (1.f + __expf(-u));
      float n = tanhf(nn + r * hn);
      float h = P.hf[idx];
      float hnew = (1.f - u) * n + u * h;
      P.hf[idx] = hnew;
      P.hb[idx] = (bf16)hnew;
      P.feat[((size_t)m * T_ + t) * 1056 + i] = hnew;
      P.obsb[idx] = (bf16)P.obs[((size_t)m * T_ + t) * OBS_ + i];
    }
    grid.sync();

    // ---- S4: pr1 [512 items split2] ; po1 [1024 items split4, h|obs K-segments] ----
    {
      TileJob j; j.valid = 0; j.ksub = 0; j.S = 1; j.lgS = 0;
      if (wgid < 512) {
        const int tile = wgid >> 1, ks = wgid & 1;
        j = { P.hb, P.w_pr1b, P.pr_b1, P.p1b, nullptr,
              DET_, DET_, HID_, 0,
              (tile & 15) * 16, (tile >> 4) * 64, ks * 512, ks * 512 + 512,
              ks, 1, 2, 1, 1 };
      } else if (wgid < 1536) {
        const int it = wgid - 512, tile = it >> 2, ks = it & 3;
        j = { (ks < 2) ? P.hb : P.obsb, P.w_po1b, P.po_b1, P.q1b, nullptr,
              DET_, DET_ + OBS_, HID_, (ks < 2) ? 0 : 1024,
              (tile & 15) * 16, (tile >> 4) * 64, ks * 512, ks * 512 + 512,
              ks, 2, 4, 1, 1 };
      }
      run_job(j, sh);
    }
    grid.sync();

    // ---- S5: pr2 [1024 items split4] ; po2 [1024 items split4] ----
    {
      TileJob j; j.valid = 0; j.ksub = 0; j.S = 1; j.lgS = 0;
      if (wgid < 1024) {
        const int tile = wgid >> 2, ks = wgid & 3;
        j = { P.p1b, P.w_pr2b, P.pr_b2, P.p2b, nullptr,
              HID_, HID_, HID_, 0,
              (tile & 15) * 16, (tile >> 4) * 64, ks * 256, ks * 256 + 256,
              ks, 2, 4, 1, 1 };
      } else {
        const int it = wgid - 1024, tile = it >> 2, ks = it & 3;
        j = { P.q1b, P.w_po2b, P.po_b2, P.q2b, nullptr,
              HID_, HID_, HID_, 0,
              (tile & 15) * 16, (tile >> 4) * 64, ks * 256, ks * 256 + 256,
              ks, 2, 4, 1, 1 };
      }
      run_job(j, sh);
    }
    grid.sync();

    // ---- S6: heads + finish, block = batch row m ----
    {
      const int m = blockIdx.x;
      const int o = tid >> 2, th = tid & 3;     // o in [0,128), th splits K=1024 into 4
      const bf16* src = ((o < 64) ? P.p2b : P.q2b) + (size_t)m * HID_ + th * 256;
      const bf16* wr  = ((o < 64) ? (P.w_phb + (size_t)o * HID_)
                                  : (P.w_qhb + (size_t)(o - 64) * HID_)) + th * 256;
      float acc = 0.f;
      #pragma unroll 4
      for (int k = 0; k < 256; k += 8) {
        bf16x8 av = *(const bf16x8*)(src + k);
        bf16x8 wv8 = *(const bf16x8*)(wr + k);
        #pragma unroll
        for (int jj = 0; jj < 8; ++jj) acc = fmaf((float)av[jj], (float)wv8[jj], acc);
      }
      sh[tid] = acc;                             // partial[o][th]
      if (tid < ACT_) sh[608 + tid] = P.actions[((size_t)m * T_ + t) * ACT_ + tid];
      __syncthreads();
      if (tid < 128) {
        const float v = sh[tid * 4] + sh[tid * 4 + 1] + sh[tid * 4 + 2] + sh[tid * 4 + 3];
        const size_t ob = ((size_t)m * T_ + t) * STO_;
        if (tid < 32) {
          P.pm[ob + tid] = v + P.pr_mb[tid];
        } else if (tid < 64) {
          float x = v + P.pr_sb[tid - 32];
          P.ps[ob + tid - 32] = __expf(fminf(fmaxf(x, -5.f), 2.f));
        } else if (tid < 96) {
          float x = v + P.po_mb[tid - 64];
          P.qm[ob + tid - 64] = x; sh[512 + tid - 64] = x;
        } else {
          float x = v + P.po_sb[tid - 96];
          x = __expf(fminf(fmaxf(x, -5.f), 2.f));
          P.qs[ob + tid - 96] = x; sh[544 + tid - 96] = x;
        }
      }
      __syncthreads();
      if (tid < STO_) {
        float z = sh[512 + tid] + sh[544 + tid] * P.eps_post[((size_t)m * T_ + t) * STO_ + tid];
        sh[576 + tid] = z;
        P.feat[((size_t)m * T_ + t) * 1056 + 1024 + tid] = z;
      }
      __syncthreads();
      // next-step x1 = relu([z,a]@in_w1^T + in_b1), K=38 fp32
      #pragma unroll
      for (int rep = 0; rep < 2; ++rep) {
        const int n = tid + rep * 512;
        const float* w = P.in_w1 + (size_t)n * 38;
        float a = P.in_b1[n];
        #pragma unroll
        for (int k = 0; k < STO_; ++k) a = fmaf(sh[576 + k], w[k], a);
        #pragma unroll
        for (int k = 0; k < ACT_; ++k) a = fmaf(sh[608 + k], w[32 + k], a);
        P.x1b[(size_t)m * HID_ + n] = (bf16)fmaxf(a, 0.f);
      }
    }
    grid.sync();
  }
}

extern "C" void kernel_launch(void* const* d_in, const int* in_sizes, int n_in,
                              void* d_out, int out_size, void* d_ws, size_t ws_size,
                              hipStream_t stream) {
  (void)in_sizes; (void)n_in; (void)out_size; (void)ws_size;
  Params P;
  P.obs      = (const float*)d_in[0];
  P.actions  = (const float*)d_in[1];
  P.eps_post = (const float*)d_in[3];   // eps_prior (d_in[2]) unused by the math
  P.in_w1 = (const float*)d_in[4];  P.in_b1 = (const float*)d_in[5];
  P.in_w2 = (const float*)d_in[6];  P.in_b2 = (const float*)d_in[7];
  P.gru_wih = (const float*)d_in[8];  P.gru_whh = (const float*)d_in[9];
  P.gru_bih = (const float*)d_in[10]; P.gru_bhh = (const float*)d_in[11];
  P.pr_w1 = (const float*)d_in[12]; P.pr_b1 = (const float*)d_in[13];
  P.pr_w2 = (const float*)d_in[14]; P.pr_b2 = (const float*)d_in[15];
  P.pr_mw = (const float*)d_in[16]; P.pr_mb = (const float*)d_in[17];
  P.pr_sw = (const float*)d_in[18]; P.pr_sb = (const float*)d_in[19];
  P.po_w1 = (const float*)d_in[20]; P.po_b1 = (const float*)d_in[21];
  P.po_w2 = (const float*)d_in[22]; P.po_b2 = (const float*)d_in[23];
  P.po_mw = (const float*)d_in[24]; P.po_mb = (const float*)d_in[25];
  P.po_sw = (const float*)d_in[26]; P.po_sb = (const float*)d_in[27];

  P.feat = (float*)d_out;
  P.pm = P.feat + (size_t)B_ * T_ * 1056;
  P.ps = P.pm + (size_t)B_ * T_ * STO_;
  P.qm = P.ps + (size_t)B_ * T_ * STO_;
  P.qs = P.qm + (size_t)B_ * T_ * STO_;

  char* wp_ = (char*)d_ws;
  auto carve = [&](size_t bytes) -> void* {
    void* r = (void*)wp_;
    wp_ += (bytes + 255) & ~(size_t)255;
    return r;
  };
  P.w_in2b = (bf16*)carve((size_t)HID_ * HID_ * 2);
  P.w_wihb = (bf16*)carve((size_t)3 * DET_ * HID_ * 2);
  P.w_whhb = (bf16*)carve((size_t)3 * DET_ * DET_ * 2);
  P.w_pr1b = (bf16*)carve((size_t)HID_ * DET_ * 2);
  P.w_pr2b = (bf16*)carve((size_t)HID_ * HID_ * 2);
  P.w_po1b = (bf16*)carve((size_t)HID_ * (DET_ + OBS_) * 2);
  P.w_po2b = (bf16*)carve((size_t)HID_ * HID_ * 2);
  P.w_phb  = (bf16*)carve((size_t)64 * HID_ * 2);
  P.w_qhb  = (bf16*)carve((size_t)64 * HID_ * 2);
  P.x1b  = (bf16*)carve((size_t)B_ * HID_ * 2);
  P.x2b  = (bf16*)carve((size_t)B_ * HID_ * 2);
  P.hb   = (bf16*)carve((size_t)B_ * DET_ * 2);
  P.p1b  = (bf16*)carve((size_t)B_ * HID_ * 2);
  P.q1b  = (bf16*)carve((size_t)B_ * HID_ * 2);
  P.p2b  = (bf16*)carve((size_t)B_ * HID_ * 2);
  P.q2b  = (bf16*)carve((size_t)B_ * HID_ * 2);
  P.obsb = (bf16*)carve((size_t)B_ * OBS_ * 2);
  P.hf   = (float*)carve((size_t)B_ * DET_ * 4);
  P.gi   = (float*)carve((size_t)B_ * 3 * DET_ * 4);
  P.gh   = (float*)carve((size_t)B_ * 3 * DET_ * 4);

  void* kp[] = { (void*)&P };
  hipLaunchCooperativeKernel((const void*)rssm_kern, dim3(256), dim3(512), kp, 0, stream);
}